// Round 22
// baseline (169.099 us; speedup 1.0000x reference)
//
#include <hip/hip_runtime.h>
#include <hip/hip_bf16.h>

#define S_LEN 2048
#define NH 16
#define DKH 64
#define DM 1024
// 1/sqrt(64) * log2(e): folded into Q at the QKV-GEMM epilogue
#define QK_SCALE_L2E 0.1803368801111244f

typedef __attribute__((ext_vector_type(8))) short bf16x8;
typedef __attribute__((ext_vector_type(4))) float f32x4;
typedef __attribute__((ext_vector_type(4))) unsigned int u32x4;

__device__ __forceinline__ unsigned short f2bf(float f) {
  unsigned int x = __builtin_bit_cast(unsigned int, f);
  x += 0x7fffu + ((x >> 16) & 1u);   // RNE
  return (unsigned short)(x >> 16);
}
__device__ __forceinline__ float bf2f(unsigned short u) {
  unsigned int x = ((unsigned int)u) << 16;
  return __builtin_bit_cast(float, x);
}
__device__ __forceinline__ float exp2a(float x) {
  float r; asm("v_exp_f32 %0, %1" : "=v"(r) : "v"(x)); return r;
}
__device__ __forceinline__ unsigned int cvtpk(float a, float b) {
  unsigned int r; asm("v_cvt_pk_bf16_f32 %0, %1, %2" : "=v"(r) : "v"(a), "v"(b)); return r;
}

__device__ __forceinline__ void gload_lds16(const void* g, void* l) {
  __builtin_amdgcn_global_load_lds(
      (const __attribute__((address_space(1))) unsigned int*)g,
      (__attribute__((address_space(3))) unsigned int*)l, 16, 0, 0);
}

// ---------------- fp32 -> bf16 conversion, all three tensors in one launch --
__global__ void cvt_all(const float* __restrict__ x,
                        const float* __restrict__ wa,
                        const float* __restrict__ wp,
                        unsigned short* __restrict__ xo,
                        unsigned short* __restrict__ wao,
                        unsigned short* __restrict__ wpo) {
  int i = (blockIdx.x * blockDim.x + threadIdx.x) * 8;
  const float* src; unsigned short* dst; int off;
  if (i < 4194304)      { src = x;  dst = xo;  off = i; }
  else if (i < 7340032) { src = wa; dst = wao; off = i - 4194304; }
  else                  { src = wp; dst = wpo; off = i - 7340032; }
  float4 a = *(const float4*)(src + off);
  float4 b = *(const float4*)(src + off + 4);
  union { unsigned short us[8]; u32x4 v; } r;
  r.us[0] = f2bf(a.x); r.us[1] = f2bf(a.y); r.us[2] = f2bf(a.z); r.us[3] = f2bf(a.w);
  r.us[4] = f2bf(b.x); r.us[5] = f2bf(b.y); r.us[6] = f2bf(b.z); r.us[7] = f2bf(b.w);
  *(u32x4*)(dst + off) = r.v;
}

// ==== 128x128 bf16 GEMM, BK=32, 2-slot LDS (32KB) -> 5 blocks/CU TLP ========
// Hazard ledger for single barrier/tile with 2 slots:
//  (1) top __syncthreads drains vmcnt: tile kt's loads were issued a FULL
//      iteration (~1100cy) earlier -> aged past L2/HBM latency, drain ~free;
//      barrier makes tile kt resident for all waves.
//  (2) STG(kt+1) -> slot cs^1: its last readers ran in iter kt-1; every
//      wave's ds_reads completed before its MFMAs (compiler lgkm), which
//      precede this barrier -> no overwrite hazard.
//  (3) ds_reads of slot cs are disjoint from the slot cs^1 writes.
// MODE 0: vt store applies the sigma kv-permutation (R20-proven).
template<int MODE>
__global__ __launch_bounds__(256, 5) void gemm_x(
    const unsigned short* __restrict__ A,   // [M,K] bf16 row-major
    const unsigned short* __restrict__ Bt,  // [N,K] bf16 row-major
    const float* __restrict__ bias,         // [N]
    float* __restrict__ Cf,                 // MODE 1
    unsigned short* __restrict__ qo,        // MODE 0
    unsigned short* __restrict__ ko,
    unsigned short* __restrict__ vto,
    int M, int N, int K)
{
  __shared__ __align__(16) char LA[2][8192];   // slot: 128 rows x 32 bf16
  __shared__ __align__(16) char LB[2][8192];   // 2 rows packed per 128B line
  int t = threadIdx.x;
  int lane = t & 63, wid = t >> 6;
  int wr = wid >> 1, wc = wid & 1;

  int bid = blockIdx.x + gridDim.x * blockIdx.y;
  int xcd = bid & 7, local = bid >> 3;
  int bx, by;
  if (MODE == 0) {
    int xm = xcd >> 1, xn = xcd & 1;        // 4 x 2 XCD layout
    by = xm * 8 + (local & 7);              // local in [0,96)
    bx = xn * 12 + (local >> 3);
  } else {
    by = xcd * 4 + (local >> 3);            // local in [0,32)
    bx = local & 7;
  }
  int m0 = by << 7, n0 = bx << 7;
  int gi = lane >> 4, c0 = lane & 15;
  int rs = t >> 3, uP = t & 7;               // rs in [0,32)

  f32x4 acc[4][4];
#pragma unroll
  for (int i = 0; i < 4; ++i)
#pragma unroll
    for (int j = 0; j < 4; ++j) acc[i][j] = (f32x4){0.f, 0.f, 0.f, 0.f};

  // staging (rule 21): LDS line p, slot s holds row 2p+(u>>2), chunk u&3,
  // u = s^(p&7).
  int u = uP ^ (rs & 7);
  int srow = 2 * rs + (u >> 2);
  int scol = (u & 3) * 8;
  const unsigned short* ap0 = A  + (size_t)(m0 + srow) * K + scol;
  const unsigned short* ap1 = ap0 + (size_t)64 * K;
  const unsigned short* bp0 = Bt + (size_t)(n0 + srow) * K + scol;
  const unsigned short* bp1 = bp0 + (size_t)64 * K;
  int la0 = rs * 128 + uP * 16, la1 = la0 + 4096;

#define STG(s)                                                     \
  do {                                                             \
    gload_lds16(ap0, LA[s] + la0); gload_lds16(ap1, LA[s] + la1);  \
    gload_lds16(bp0, LB[s] + la0); gload_lds16(bp1, LB[s] + la1);  \
    ap0 += 32; ap1 += 32; bp0 += 32; bp1 += 32;                    \
  } while (0)

  const int NT = K >> 5;                     // 32 tiles at K=1024
  STG(0);                                    // depth-1 prologue

  for (int kt = 0; kt < NT; ++kt) {
    int cs = kt & 1;
    __syncthreads();   // drain (tile kt loads aged ~1 iter) + order slot reuse

    if (kt + 1 < NT) STG(cs ^ 1);            // issue next tile first

    const char* cA = LA[cs];
    const char* cB = LB[cs];
    bf16x8 af[4], bfr[4];
#pragma unroll
    for (int m = 0; m < 4; ++m) {
      int ra = wr * 64 + m * 16 + c0;
      int p = ra >> 1;
      af[m] = *(const bf16x8*)(cA + p * 128 + ((((ra & 1) * 4 + gi) ^ (p & 7)) * 16));
    }
#pragma unroll
    for (int n = 0; n < 4; ++n) {
      int rb = wc * 64 + n * 16 + c0;
      int p = rb >> 1;
      bfr[n] = *(const bf16x8*)(cB + p * 128 + ((((rb & 1) * 4 + gi) ^ (p & 7)) * 16));
    }

    __builtin_amdgcn_s_setprio(1);
#pragma unroll
    for (int m = 0; m < 4; ++m)
#pragma unroll
      for (int n = 0; n < 4; ++n)
        acc[m][n] = __builtin_amdgcn_mfma_f32_16x16x32_bf16(af[m], bfr[n], acc[m][n], 0, 0, 0);
    __builtin_amdgcn_s_setprio(0);
  }
#undef STG

#pragma unroll
  for (int i = 0; i < 4; ++i) {
#pragma unroll
    for (int j = 0; j < 4; ++j) {
#pragma unroll
      for (int rI = 0; rI < 4; ++rI) {
        int m = m0 + wr * 64 + i * 16 + gi * 4 + rI;
        int n = n0 + wc * 64 + j * 16 + c0;
        float v = acc[i][j][rI] + bias[n];
        if (MODE == 1) {
          Cf[(size_t)m * N + n] = v;
        } else {
          int b = m >> 11, s = m & 2047;
          int which = n >> 10, w2 = n & 1023;
          int h = w2 >> 6, dk = w2 & 63;
          size_t hoff = (size_t)(b * NH + h);
          if (which == 0) {
            qo[(hoff * S_LEN + s) * DKH + dk] = f2bf(v * QK_SCALE_L2E);
          } else if (which == 1) {
            ko[(hoff * S_LEN + s) * DKH + dk] = f2bf(v);
          } else {
            // V transposed + sigma kv-permutation within each 64-row tile
            int sl = s & 63;
            int qp = (sl & 32) + ((sl & 12) << 1) + ((sl & 16) >> 2) + (sl & 3);
            vto[(hoff * DKH + dk) * S_LEN + (s & ~63) + qp] = f2bf(v);
          }
        }
      }
    }
  }
}

// ==== 128x64 bf16 GEMM for proj: 2-slot LDS (24KB), same single-barrier =====
__global__ __launch_bounds__(256, 4) void gemm_h(
    const unsigned short* __restrict__ A,   // [M,K] bf16 row-major
    const unsigned short* __restrict__ Bt,  // [N,K] bf16 row-major
    const float* __restrict__ bias,         // [N]
    float* __restrict__ Cf,                 // [M,N] fp32 out
    int M, int N, int K)
{
  __shared__ __align__(16) char LA[2][8192];   // 128 rows x 32 bf16
  __shared__ __align__(16) char LB[2][4096];   // 64 rows x 32 bf16
  int t = threadIdx.x;
  int lane = t & 63, wid = t >> 6;
  int wr = wid >> 1, wc = wid & 1;

  int bid = blockIdx.x + gridDim.x * blockIdx.y;
  int xcd = bid & 7, local = bid >> 3;      // local in [0,64)
  int by = xcd * 4 + (local >> 4);
  int bx = local & 15;
  int m0 = by << 7, n0 = bx << 6;
  int gi = lane >> 4, c0 = lane & 15;
  int rs = t >> 3, uP = t & 7;               // rs in [0,32)

  f32x4 acc[4][2];
#pragma unroll
  for (int i = 0; i < 4; ++i)
#pragma unroll
    for (int j = 0; j < 2; ++j) acc[i][j] = (f32x4){0.f, 0.f, 0.f, 0.f};

  int u = uP ^ (rs & 7);
  int srow = 2 * rs + (u >> 2);
  int scol = (u & 3) * 8;
  const unsigned short* ap0 = A  + (size_t)(m0 + srow) * K + scol;
  const unsigned short* ap1 = ap0 + (size_t)64 * K;
  const unsigned short* bp0 = Bt + (size_t)(n0 + srow) * K + scol;
  int la0 = rs * 128 + uP * 16, la1 = la0 + 4096;

#define STGH(s)                                                    \
  do {                                                             \
    gload_lds16(ap0, LA[s] + la0); gload_lds16(ap1, LA[s] + la1);  \
    gload_lds16(bp0, LB[s] + la0);                                 \
    ap0 += 32; ap1 += 32; bp0 += 32;                               \
  } while (0)

  const int NT = K >> 5;
  STGH(0);                                   // depth-1 prologue

  for (int kt = 0; kt < NT; ++kt) {
    int cs = kt & 1;
    __syncthreads();

    if (kt + 1 < NT) STGH(cs ^ 1);

    const char* cA = LA[cs];
    const char* cB = LB[cs];
    bf16x8 af[4], bfr[2];
#pragma unroll
    for (int m = 0; m < 4; ++m) {
      int ra = wr * 64 + m * 16 + c0;
      int p = ra >> 1;
      af[m] = *(const bf16x8*)(cA + p * 128 + ((((ra & 1) * 4 + gi) ^ (p & 7)) * 16));
    }
#pragma unroll
    for (int n = 0; n < 2; ++n) {
      int rb = wc * 32 + n * 16 + c0;
      int p = rb >> 1;
      bfr[n] = *(const bf16x8*)(cB + p * 128 + ((((rb & 1) * 4 + gi) ^ (p & 7)) * 16));
    }

    __builtin_amdgcn_s_setprio(1);
#pragma unroll
    for (int m = 0; m < 4; ++m)
#pragma unroll
      for (int n = 0; n < 2; ++n)
        acc[m][n] = __builtin_amdgcn_mfma_f32_16x16x32_bf16(af[m], bfr[n], acc[m][n], 0, 0, 0);
    __builtin_amdgcn_s_setprio(0);
  }
#undef STGH

  float bias_v[2];
#pragma unroll
  for (int n = 0; n < 2; ++n) bias_v[n] = bias[n0 + wc * 32 + n * 16 + c0];

#pragma unroll
  for (int i = 0; i < 4; ++i) {
#pragma unroll
    for (int j = 0; j < 2; ++j) {
#pragma unroll
      for (int rI = 0; rI < 4; ++rI) {
        int m = m0 + wr * 64 + i * 16 + gi * 4 + rI;
        int n = n0 + wc * 32 + j * 16 + c0;
        Cf[(size_t)m * N + n] = acc[i][j][rI] + bias_v[j];
      }
    }
  }
}

// ---------------- split-KV flash attention work table (LPT order) -----------
struct WorkItem { unsigned char qt, t0, nt; };
__device__ __constant__ WorkItem g_items[48] = {
  {15,0,16},
  {16,0,16},{17,0,16},{18,0,16},{19,0,16},{20,0,16},{21,0,16},{22,0,16},{23,0,16},
  {24,0,16},{25,0,16},{26,0,16},{27,0,16},{28,0,16},{29,0,16},{30,0,16},{31,0,16},
  {31,16,16},
  {14,0,15},{30,16,15},
  {13,0,14},{29,16,14},
  {12,0,13},{28,16,13},
  {11,0,12},{27,16,12},
  {10,0,11},{26,16,11},
  { 9,0,10},{25,16,10},
  { 8,0, 9},{24,16, 9},
  { 7,0, 8},{23,16, 8},
  { 6,0, 7},{22,16, 7},
  { 5,0, 6},{21,16, 6},
  { 4,0, 5},{20,16, 5},
  { 3,0, 4},{19,16, 4},
  { 2,0, 3},{18,16, 3},
  { 1,0, 2},{17,16, 2},
  { 0,0, 1},{16,16, 1},
};

// ---------------- flash attention (partial), swapped-QK^T in-reg softmax ----
// sigma-permuted V (zero-shuffle PV), T13 defer-max, direct-write qt<16,
// early V-stage + lgkm-only mid barrier, deferred l-reduction. (R21-proven)
__global__ __launch_bounds__(256, 6) void attn_part(
    const unsigned short* __restrict__ Q,   // [BH, S, 64] bf16, pre-scaled
    const unsigned short* __restrict__ Kb,  // [BH, S, 64] bf16
    const unsigned short* __restrict__ Vt,  // [BH, 64, S] bf16, sigma-permuted
    unsigned short* __restrict__ pO,        // [1536][64][64] bf16
    float* __restrict__ pm,                 // [1536][64]
    float* __restrict__ pl,                 // [1536][64]
    unsigned short* __restrict__ Out)       // [B*S, 1024] bf16
{
  __shared__ __align__(16) char kbuf[64 * 128];
  __shared__ __align__(16) char vbuf[2][64 * 128];
  int t = threadIdx.x;
  int lane = t & 63, wid = t >> 6;
  int gi = lane >> 4, c0 = lane & 15;
  int bid = blockIdx.x + 48 * blockIdx.y;
  int xcd = bid & 7, local = bid >> 3;      // local in [0,192)
  int item = local >> 2;
  int bh = xcd * 4 + (local & 3);
  WorkItem wi = g_items[item];
  int qt = wi.qt, tile0 = wi.t0, nt = wi.nt;
  int pid = bh * 48 + (tile0 ? (32 + qt - 16) : qt);
  int q0 = qt << 6;
  const unsigned short* Qh = Q  + (size_t)bh * S_LEN * DKH;
  const unsigned short* Kh = Kb + (size_t)bh * S_LEN * DKH;
  const unsigned short* Vh = Vt + (size_t)bh * DKH * S_LEN;

  bf16x8 qf[2];
  {
    int qrow = q0 + wid * 16 + c0;
#pragma unroll
    for (int ks = 0; ks < 2; ++ks)
      qf[ks] = *(const bf16x8*)(Qh + (size_t)qrow * DKH + ks * 32 + gi * 8);
  }

  float mrow = -1e30f, lrow = 0.f;          // lrow: per-lane partial
  f32x4 o[4];
#pragma unroll
  for (int i = 0; i < 4; ++i) o[i] = (f32x4){0, 0, 0, 0};

  int rs = t >> 3, uP = t & 7;
  int q_abs = q0 + wid * 16 + c0;

  int c8 = uP ^ (rs & 7);
  const unsigned short* kp0 = Kh + ((size_t)(tile0 * 64 + rs) * DKH) + c8 * 8;
  const unsigned short* kp1 = kp0 + 32 * DKH;
  const unsigned short* vp0 = Vh + (size_t)rs * S_LEN + tile0 * 64 + c8 * 8;
  const unsigned short* vp1 = vp0 + (size_t)32 * S_LEN;
  char* klds0 = kbuf + rs * 128 + uP * 16;
  char* klds1 = klds0 + 32 * 128;
  int vlds_off0 = rs * 128 + uP * 16;

  gload_lds16(kp0, klds0);
  gload_lds16(kp1, klds1);
  gload_lds16(vp0, vbuf[0] + vlds_off0);
  gload_lds16(vp1, vbuf[0] + vlds_off0 + 32 * 128);
  kp0 += 64 * DKH; kp1 += 64 * DKH; vp0 += 64; vp1 += 64;

  for (int tt = 0; tt < nt; ++tt) {
    int tile = tile0 + tt;
    int kv0 = tile << 6;
    __syncthreads();   // vmcnt+lgkm drain: K(t), V(t) resident

    // EARLY V-stage for t+1 (V double-buffered; readers ordered by barrier)
    if (tt + 1 < nt) {
      char* vb = vbuf[(tt + 1) & 1];
      gload_lds16(vp0, vb + vlds_off0);
      gload_lds16(vp1, vb + vlds_off0 + 32 * 128);
      vp0 += 64; vp1 += 64;
    }

    f32x4 sc[4];
    __builtin_amdgcn_s_setprio(1);
#pragma unroll
    for (int f = 0; f < 4; ++f) {
      f32x4 s = (f32x4){0, 0, 0, 0};
#pragma unroll
      for (int ks = 0; ks < 2; ++ks) {
        int rb = f * 16 + c0;
        int uL = ks * 4 + gi;
        bf16x8 kf = *(const bf16x8*)(kbuf + rb * 128 + ((uL ^ (rb & 7)) * 16));
        s = __builtin_amdgcn_mfma_f32_16x16x32_bf16(kf, qf[ks], s, 0, 0, 0);
      }
      sc[f] = s;
    }
    __builtin_amdgcn_s_setprio(0);
    // mid barrier: lgkm-only; must NOT drain vmcnt (early V loads in flight)
    asm volatile("s_waitcnt lgkmcnt(0)" ::: "memory");
    __builtin_amdgcn_s_barrier();

    if (tt + 1 < nt) {                       // K stages after kbuf is free
      gload_lds16(kp0, klds0);
      gload_lds16(kp1, klds1);
      kp0 += 64 * DKH; kp1 += 64 * DKH;
    }

    if (tile == qt) {
      int kvb = kv0 + gi * 4;
#pragma unroll
      for (int f = 0; f < 4; ++f)
#pragma unroll
        for (int i = 0; i < 4; ++i)
          if (kvb + f * 16 + i > q_abs) sc[f][i] = -1e30f;
    }

    float m01 = fmaxf(fmaxf(sc[0][0], sc[0][1]), fmaxf(sc[0][2], sc[0][3]));
    float m23 = fmaxf(fmaxf(sc[1][0], sc[1][1]), fmaxf(sc[1][2], sc[1][3]));
    float m45 = fmaxf(fmaxf(sc[2][0], sc[2][1]), fmaxf(sc[2][2], sc[2][3]));
    float m67 = fmaxf(fmaxf(sc[3][0], sc[3][1]), fmaxf(sc[3][2], sc[3][3]));
    float tmax = fmaxf(fmaxf(m01, m23), fmaxf(m45, m67));
    tmax = fmaxf(tmax, __shfl_xor(tmax, 16));
    tmax = fmaxf(tmax, __shfl_xor(tmax, 32));

    float alpha = 1.f;
    if (__any(tmax > mrow + 8.f)) {   // T13 defer-max
      float mnew = fmaxf(mrow, tmax);
      alpha = exp2a(mrow - mnew);
      mrow = mnew;
      float af0 = __shfl(alpha, gi * 4 + 0);
      float af1 = __shfl(alpha, gi * 4 + 1);
      float af2 = __shfl(alpha, gi * 4 + 2);
      float af3 = __shfl(alpha, gi * 4 + 3);
#pragma unroll
      for (int df = 0; df < 4; ++df) {
        o[df][0] *= af0; o[df][1] *= af1; o[df][2] *= af2; o[df][3] *= af3;
      }
    }

    float ps0 = 0, ps1 = 0, ps2 = 0, ps3 = 0;
#pragma unroll
    for (int f = 0; f < 4; ++f) {
      float p0 = exp2a(sc[f][0] - mrow);
      float p1 = exp2a(sc[f][1] - mrow);
      float p2 = exp2a(sc[f][2] - mrow);
      float p3 = exp2a(sc[f][3] - mrow);
      sc[f][0] = p0; sc[f][1] = p1; sc[f][2] = p2; sc[f][3] = p3;
      ps0 += p0; ps1 += p1; ps2 += p2; ps3 += p3;
    }
    lrow = lrow * alpha + ((ps0 + ps1) + (ps2 + ps3));

    // P -> bf16: lane-local PV A-fragments (V rows sigma-permuted to match)
    {
      const char* vcur = vbuf[tt & 1];
#pragma unroll
      for (int ks = 0; ks < 2; ++ks) {
        union { unsigned int w[4]; bf16x8 v; } pa;
        pa.w[0] = cvtpk(sc[2 * ks][0],     sc[2 * ks][1]);
        pa.w[1] = cvtpk(sc[2 * ks][2],     sc[2 * ks][3]);
        pa.w[2] = cvtpk(sc[2 * ks + 1][0], sc[2 * ks + 1][1]);
        pa.w[3] = cvtpk(sc[2 * ks + 1][2], sc[2 * ks + 1][3]);
        __builtin_amdgcn_s_setprio(1);
#pragma unroll
        for (int df = 0; df < 4; ++df) {
          int rv = df * 16 + c0;
          int uL = ks * 4 + gi;
          bf16x8 vf = *(const bf16x8*)(vcur + rv * 128 + ((uL ^ (rv & 7)) * 16));
          o[df] = __builtin_amdgcn_mfma_f32_16x16x32_bf16(pa.v, vf, o[df], 0, 0, 0);
        }
        __builtin_amdgcn_s_setprio(0);
      }
    }
  }

  // epilogue: complete the deferred l-reduction (once per block)
  lrow += __shfl_xor(lrow, 16);
  lrow += __shfl_xor(lrow, 32);

  if (qt < 16) {
    // single-chunk row block: normalize here, write directly to Out
    int b = bh >> 4, h = bh & 15;
    float linv = 1.0f / lrow;                 // lane holds l for q-row c0
#pragma unroll
    for (int i = 0; i < 4; ++i) {
      float rli = __shfl(linv, gi * 4 + i);   // l for output row gi*4+i
      int r = wid * 16 + gi * 4 + i;
      size_t base = ((size_t)(b * S_LEN) + (q0 + r)) * DM + h * DKH;
#pragma unroll
      for (int df = 0; df < 4; ++df)
        Out[base + df * 16 + c0] = f2bf(o[df][i] * rli);
    }
  } else {
    unsigned short* po = pO + (size_t)pid * 4096;
#pragma unroll
    for (int i = 0; i < 4; ++i) {
      int r = wid * 16 + gi * 4 + i;
#pragma unroll
      for (int df = 0; df < 4; ++df)
        po[r * 64 + df * 16 + c0] = f2bf(o[df][i]);
    }
    if (lane < 16) {
      pm[pid * 64 + wid * 16 + c0] = mrow;
      pl[pid * 64 + wid * 16 + c0] = lrow;
    }
  }
}

// ---------------- combine partials (qt >= 16 only) -> Out ------------------
__global__ __launch_bounds__(256) void attn_combine(
    const unsigned short* __restrict__ pO,
    const float* __restrict__ pm,
    const float* __restrict__ pl,
    unsigned short* __restrict__ Out)
{
  int qt = blockIdx.x + 16, bh = blockIdx.y;
  int t = threadIdx.x;
  int r = t >> 2, cseg = (t & 3) * 16;
  int pid0 = bh * 48 + qt;
  int pid1 = bh * 48 + 32 + qt - 16;

  float m0 = pm[pid0 * 64 + r];
  float l0 = pl[pid0 * 64 + r];
  float m1 = pm[pid1 * 64 + r];
  float l1 = pl[pid1 * 64 + r];
  float M = fmaxf(m0, m1);
  float w0 = exp2a(m0 - M);
  float w1 = exp2a(m1 - M);
  float l = w0 * l0 + w1 * l1;
  float rl = 1.0f / l;

  const unsigned short* o0 = pO + (size_t)pid0 * 4096 + r * 64 + cseg;
  const unsigned short* o1 = pO + (size_t)pid1 * 4096 + r * 64 + cseg;
  int b = bh >> 4, h = bh & 15;
  size_t base = ((size_t)(b * S_LEN) + (qt * 64 + r)) * DM + h * DKH + cseg;

  bf16x8 a0 = *(const bf16x8*)o0;
  bf16x8 a1 = *(const bf16x8*)(o0 + 8);
  bf16x8 b0 = *(const bf16x8*)o1;
  bf16x8 b1 = *(const bf16x8*)(o1 + 8);
  unsigned short res[16];
#pragma unroll
  for (int j = 0; j < 8; ++j) {
    res[j]     = f2bf((w0 * bf2f((unsigned short)a0[j]) + w1 * bf2f((unsigned short)b0[j])) * rl);
    res[j + 8] = f2bf((w0 * bf2f((unsigned short)a1[j]) + w1 * bf2f((unsigned short)b1[j])) * rl);
  }
  *(u32x4*)(Out + base)     = *(u32x4*)res;
  *(u32x4*)(Out + base + 8) = *(u32x4*)(res + 8);
}

// ----------------------------------------------------------------------------
extern "C" void kernel_launch(void* const* d_in, const int* in_sizes, int n_in,
                              void* d_out, int out_size, void* d_ws, size_t ws_size,
                              hipStream_t stream) {
  const float* x       = (const float*)d_in[0];
  const float* w_atten = (const float*)d_in[1];
  const float* b_atten = (const float*)d_in[2];
  const float* w_proj  = (const float*)d_in[3];
  const float* b_proj  = (const float*)d_in[4];
  float* out = (float*)d_out;
  char* ws = (char*)d_ws;

  unsigned short* x_bf  = (unsigned short*)(ws);
  unsigned short* wa_bf = (unsigned short*)(ws + ((size_t)8  << 20));
  unsigned short* wp_bf = (unsigned short*)(ws + ((size_t)14 << 20));
  unsigned short* q_bf  = (unsigned short*)(ws + ((size_t)16 << 20));
  unsigned short* k_bf  = (unsigned short*)(ws + ((size_t)24 << 20));
  unsigned short* vt_bf = (unsigned short*)(ws + ((size_t)32 << 20));
  unsigned short* at_bf = (unsigned short*)(ws + ((size_t)40 << 20));
  // partial buffers overlay x_bf/wa_bf (dead after gemm0)
  unsigned short* pO = (unsigned short*)(ws);
  float* pm = (float*)(ws + 12582912);
  float* pl = (float*)(ws + 12976128);

  cvt_all<<<4096, 256, 0, stream>>>(x, w_atten, w_proj, x_bf, wa_bf, wp_bf);

  gemm_x<0><<<dim3(24, 32), 256, 0, stream>>>(x_bf, wa_bf, b_atten, nullptr,
                                              q_bf, k_bf, vt_bf, 4096, 3072, 1024);
  attn_part<<<dim3(48, 32), 256, 0, stream>>>(q_bf, k_bf, vt_bf, pO, pm, pl, at_bf);
  attn_combine<<<dim3(16, 32), 256, 0, stream>>>(pO, pm, pl, at_bf);
  gemm_h<<<dim3(16, 32), 256, 0, stream>>>(at_bf, wp_bf, b_proj, out,
                                           4096, 1024, 1024);
}

// Round 23
// 109.480 us; speedup vs baseline: 1.5446x; 1.5446x over previous
//
#include <hip/hip_runtime.h>
#include <hip/hip_bf16.h>

#define S_LEN 2048
#define NH 16
#define DKH 64
#define DM 1024
// 1/sqrt(64) * log2(e): folded into Q at the QKV-GEMM epilogue
#define QK_SCALE_L2E 0.1803368801111244f

typedef __attribute__((ext_vector_type(8))) short bf16x8;
typedef __attribute__((ext_vector_type(4))) float f32x4;
typedef __attribute__((ext_vector_type(4))) unsigned int u32x4;

__device__ __forceinline__ unsigned short f2bf(float f) {
  unsigned int x = __builtin_bit_cast(unsigned int, f);
  x += 0x7fffu + ((x >> 16) & 1u);   // RNE
  return (unsigned short)(x >> 16);
}
__device__ __forceinline__ float bf2f(unsigned short u) {
  unsigned int x = ((unsigned int)u) << 16;
  return __builtin_bit_cast(float, x);
}
__device__ __forceinline__ float exp2a(float x) {
  float r; asm("v_exp_f32 %0, %1" : "=v"(r) : "v"(x)); return r;
}
__device__ __forceinline__ unsigned int cvtpk(float a, float b) {
  unsigned int r; asm("v_cvt_pk_bf16_f32 %0, %1, %2" : "=v"(r) : "v"(a), "v"(b)); return r;
}

__device__ __forceinline__ void gload_lds16(const void* g, void* l) {
  __builtin_amdgcn_global_load_lds(
      (const __attribute__((address_space(1))) unsigned int*)g,
      (__attribute__((address_space(3))) unsigned int*)l, 16, 0, 0);
}

// ---------------- fp32 -> bf16 conversion, all three tensors in one launch --
__global__ void cvt_all(const float* __restrict__ x,
                        const float* __restrict__ wa,
                        const float* __restrict__ wp,
                        unsigned short* __restrict__ xo,
                        unsigned short* __restrict__ wao,
                        unsigned short* __restrict__ wpo) {
  int i = (blockIdx.x * blockDim.x + threadIdx.x) * 8;
  const float* src; unsigned short* dst; int off;
  if (i < 4194304)      { src = x;  dst = xo;  off = i; }
  else if (i < 7340032) { src = wa; dst = wao; off = i - 4194304; }
  else                  { src = wp; dst = wpo; off = i - 7340032; }
  float4 a = *(const float4*)(src + off);
  float4 b = *(const float4*)(src + off + 4);
  union { unsigned short us[8]; u32x4 v; } r;
  r.us[0] = f2bf(a.x); r.us[1] = f2bf(a.y); r.us[2] = f2bf(a.z); r.us[3] = f2bf(a.w);
  r.us[4] = f2bf(b.x); r.us[5] = f2bf(b.y); r.us[6] = f2bf(b.z); r.us[7] = f2bf(b.w);
  *(u32x4*)(dst + off) = r.v;
}

// ==== 128x128 bf16 GEMM, BK=32, 3-slot LDS, depth-2 prefetch, XCD-chunked ===
// (R9-proven: 47.2us QKV; R22 showed the 3rd slot IS the ageing mechanism --
// with 2 slots the vmcnt drain targets ~300cy-old loads and stalls.)
// MODE 0: vt store applies the sigma kv-permutation (R20-proven) so the
// attention PV A-fragment is lane-local.
template<int MODE>
__global__ __launch_bounds__(256, 3) void gemm_x(
    const unsigned short* __restrict__ A,   // [M,K] bf16 row-major
    const unsigned short* __restrict__ Bt,  // [N,K] bf16 row-major
    const float* __restrict__ bias,         // [N]
    float* __restrict__ Cf,                 // MODE 1
    unsigned short* __restrict__ qo,        // MODE 0
    unsigned short* __restrict__ ko,
    unsigned short* __restrict__ vto,
    int M, int N, int K)
{
  __shared__ __align__(16) char LA[3][8192];   // slot: 128 rows x 32 bf16
  __shared__ __align__(16) char LB[3][8192];   // 2 rows packed per 128B line
  int t = threadIdx.x;
  int lane = t & 63, wid = t >> 6;
  int wr = wid >> 1, wc = wid & 1;

  int bid = blockIdx.x + gridDim.x * blockIdx.y;
  int xcd = bid & 7, local = bid >> 3;
  int bx, by;
  if (MODE == 0) {
    int xm = xcd >> 1, xn = xcd & 1;        // 4 x 2 XCD layout
    by = xm * 8 + (local & 7);              // local in [0,96)
    bx = xn * 12 + (local >> 3);
  } else {
    by = xcd * 4 + (local >> 3);            // local in [0,32)
    bx = local & 7;
  }
  int m0 = by << 7, n0 = bx << 7;
  int gi = lane >> 4, c0 = lane & 15;
  int rs = t >> 3, uP = t & 7;               // rs in [0,32)

  f32x4 acc[4][4];
#pragma unroll
  for (int i = 0; i < 4; ++i)
#pragma unroll
    for (int j = 0; j < 4; ++j) acc[i][j] = (f32x4){0.f, 0.f, 0.f, 0.f};

  // staging (rule 21): LDS line p, slot s holds row 2p+(u>>2), chunk u&3,
  // u = s^(p&7).
  int u = uP ^ (rs & 7);
  int srow = 2 * rs + (u >> 2);
  int scol = (u & 3) * 8;
  const unsigned short* ap0 = A  + (size_t)(m0 + srow) * K + scol;
  const unsigned short* ap1 = ap0 + (size_t)64 * K;
  const unsigned short* bp0 = Bt + (size_t)(n0 + srow) * K + scol;
  const unsigned short* bp1 = bp0 + (size_t)64 * K;
  int la0 = rs * 128 + uP * 16, la1 = la0 + 4096;

#define STG(s)                                                     \
  do {                                                             \
    gload_lds16(ap0, LA[s] + la0); gload_lds16(ap1, LA[s] + la1);  \
    gload_lds16(bp0, LB[s] + la0); gload_lds16(bp1, LB[s] + la1);  \
    ap0 += 32; ap1 += 32; bp0 += 32; bp1 += 32;                    \
  } while (0)

  const int NT = K >> 5;                     // 32 tiles at K=1024
  STG(0); STG(1);                            // depth-2 prologue (8 loads)

  int cs = 0, ss = 2;
  for (int kt = 0; kt < NT; ++kt) {
    if (kt < NT - 1) asm volatile("s_waitcnt vmcnt(4)" ::: "memory");
    else             asm volatile("s_waitcnt vmcnt(0)" ::: "memory");
    __builtin_amdgcn_s_barrier();

    if (kt < NT - 2) STG(ss);                // issue next loads first

    const char* cA = LA[cs];
    const char* cB = LB[cs];
    bf16x8 af[4], bfr[4];
#pragma unroll
    for (int m = 0; m < 4; ++m) {
      int ra = wr * 64 + m * 16 + c0;
      int p = ra >> 1;
      af[m] = *(const bf16x8*)(cA + p * 128 + ((((ra & 1) * 4 + gi) ^ (p & 7)) * 16));
    }
#pragma unroll
    for (int n = 0; n < 4; ++n) {
      int rb = wc * 64 + n * 16 + c0;
      int p = rb >> 1;
      bfr[n] = *(const bf16x8*)(cB + p * 128 + ((((rb & 1) * 4 + gi) ^ (p & 7)) * 16));
    }

    __builtin_amdgcn_s_setprio(1);
#pragma unroll
    for (int m = 0; m < 4; ++m)
#pragma unroll
      for (int n = 0; n < 4; ++n)
        acc[m][n] = __builtin_amdgcn_mfma_f32_16x16x32_bf16(af[m], bfr[n], acc[m][n], 0, 0, 0);
    __builtin_amdgcn_s_setprio(0);

    cs = (cs == 2) ? 0 : cs + 1;
    ss = (ss == 2) ? 0 : ss + 1;
  }
#undef STG

#pragma unroll
  for (int i = 0; i < 4; ++i) {
#pragma unroll
    for (int j = 0; j < 4; ++j) {
#pragma unroll
      for (int rI = 0; rI < 4; ++rI) {
        int m = m0 + wr * 64 + i * 16 + gi * 4 + rI;
        int n = n0 + wc * 64 + j * 16 + c0;
        float v = acc[i][j][rI] + bias[n];
        if (MODE == 1) {
          Cf[(size_t)m * N + n] = v;
        } else {
          int b = m >> 11, s = m & 2047;
          int which = n >> 10, w2 = n & 1023;
          int h = w2 >> 6, dk = w2 & 63;
          size_t hoff = (size_t)(b * NH + h);
          if (which == 0) {
            qo[(hoff * S_LEN + s) * DKH + dk] = f2bf(v * QK_SCALE_L2E);
          } else if (which == 1) {
            ko[(hoff * S_LEN + s) * DKH + dk] = f2bf(v);
          } else {
            // V transposed + sigma kv-permutation within each 64-row tile
            int sl = s & 63;
            int qp = (sl & 32) + ((sl & 12) << 1) + ((sl & 16) >> 2) + (sl & 3);
            vto[(hoff * DKH + dk) * S_LEN + (s & ~63) + qp] = f2bf(v);
          }
        }
      }
    }
  }
}

// ==== 128x64 bf16 GEMM for proj: 3-slot LDS, 512 blocks -> 2+ blocks/CU =====
__global__ __launch_bounds__(256, 4) void gemm_h(
    const unsigned short* __restrict__ A,   // [M,K] bf16 row-major
    const unsigned short* __restrict__ Bt,  // [N,K] bf16 row-major
    const float* __restrict__ bias,         // [N]
    float* __restrict__ Cf,                 // [M,N] fp32 out
    int M, int N, int K)
{
  __shared__ __align__(16) char LA[3][8192];   // 128 rows x 32 bf16
  __shared__ __align__(16) char LB[3][4096];   // 64 rows x 32 bf16
  int t = threadIdx.x;
  int lane = t & 63, wid = t >> 6;
  int wr = wid >> 1, wc = wid & 1;

  int bid = blockIdx.x + gridDim.x * blockIdx.y;
  int xcd = bid & 7, local = bid >> 3;      // local in [0,64)
  int by = xcd * 4 + (local >> 4);
  int bx = local & 15;
  int m0 = by << 7, n0 = bx << 6;
  int gi = lane >> 4, c0 = lane & 15;
  int rs = t >> 3, uP = t & 7;               // rs in [0,32)

  f32x4 acc[4][2];
#pragma unroll
  for (int i = 0; i < 4; ++i)
#pragma unroll
    for (int j = 0; j < 2; ++j) acc[i][j] = (f32x4){0.f, 0.f, 0.f, 0.f};

  int u = uP ^ (rs & 7);
  int srow = 2 * rs + (u >> 2);
  int scol = (u & 3) * 8;
  const unsigned short* ap0 = A  + (size_t)(m0 + srow) * K + scol;
  const unsigned short* ap1 = ap0 + (size_t)64 * K;
  const unsigned short* bp0 = Bt + (size_t)(n0 + srow) * K + scol;
  int la0 = rs * 128 + uP * 16, la1 = la0 + 4096;

#define STGH(s)                                                    \
  do {                                                             \
    gload_lds16(ap0, LA[s] + la0); gload_lds16(ap1, LA[s] + la1);  \
    gload_lds16(bp0, LB[s] + la0);                                 \
    ap0 += 32; ap1 += 32; bp0 += 32;                               \
  } while (0)

  const int NT = K >> 5;
  STGH(0); STGH(1);                          // depth-2 prologue (6 loads)

  int cs = 0, ss = 2;
  for (int kt = 0; kt < NT; ++kt) {
    if (kt < NT - 1) asm volatile("s_waitcnt vmcnt(3)" ::: "memory");
    else             asm volatile("s_waitcnt vmcnt(0)" ::: "memory");
    __builtin_amdgcn_s_barrier();

    if (kt < NT - 2) STGH(ss);

    const char* cA = LA[cs];
    const char* cB = LB[cs];
    bf16x8 af[4], bfr[2];
#pragma unroll
    for (int m = 0; m < 4; ++m) {
      int ra = wr * 64 + m * 16 + c0;
      int p = ra >> 1;
      af[m] = *(const bf16x8*)(cA + p * 128 + ((((ra & 1) * 4 + gi) ^ (p & 7)) * 16));
    }
#pragma unroll
    for (int n = 0; n < 2; ++n) {
      int rb = wc * 32 + n * 16 + c0;
      int p = rb >> 1;
      bfr[n] = *(const bf16x8*)(cB + p * 128 + ((((rb & 1) * 4 + gi) ^ (p & 7)) * 16));
    }

    __builtin_amdgcn_s_setprio(1);
#pragma unroll
    for (int m = 0; m < 4; ++m)
#pragma unroll
      for (int n = 0; n < 2; ++n)
        acc[m][n] = __builtin_amdgcn_mfma_f32_16x16x32_bf16(af[m], bfr[n], acc[m][n], 0, 0, 0);
    __builtin_amdgcn_s_setprio(0);

    cs = (cs == 2) ? 0 : cs + 1;
    ss = (ss == 2) ? 0 : ss + 1;
  }
#undef STGH

  float bias_v[2];
#pragma unroll
  for (int n = 0; n < 2; ++n) bias_v[n] = bias[n0 + wc * 32 + n * 16 + c0];

#pragma unroll
  for (int i = 0; i < 4; ++i) {
#pragma unroll
    for (int j = 0; j < 2; ++j) {
#pragma unroll
      for (int rI = 0; rI < 4; ++rI) {
        int m = m0 + wr * 64 + i * 16 + gi * 4 + rI;
        int n = n0 + wc * 32 + j * 16 + c0;
        Cf[(size_t)m * N + n] = acc[i][j][rI] + bias_v[j];
      }
    }
  }
}

// ---------------- split-KV flash attention work table (LPT order) -----------
struct WorkItem { unsigned char qt, t0, nt; };
__device__ __constant__ WorkItem g_items[48] = {
  {15,0,16},
  {16,0,16},{17,0,16},{18,0,16},{19,0,16},{20,0,16},{21,0,16},{22,0,16},{23,0,16},
  {24,0,16},{25,0,16},{26,0,16},{27,0,16},{28,0,16},{29,0,16},{30,0,16},{31,0,16},
  {31,16,16},
  {14,0,15},{30,16,15},
  {13,0,14},{29,16,14},
  {12,0,13},{28,16,13},
  {11,0,12},{27,16,12},
  {10,0,11},{26,16,11},
  { 9,0,10},{25,16,10},
  { 8,0, 9},{24,16, 9},
  { 7,0, 8},{23,16, 8},
  { 6,0, 7},{22,16, 7},
  { 5,0, 6},{21,16, 6},
  { 4,0, 5},{20,16, 5},
  { 3,0, 4},{19,16, 4},
  { 2,0, 3},{18,16, 3},
  { 1,0, 2},{17,16, 2},
  { 0,0, 1},{16,16, 1},
};

// ---------------- flash attention (partial), swapped-QK^T in-reg softmax ----
// sigma-permuted V (zero-shuffle PV), T13 defer-max, direct-write qt<16,
// early V-stage + lgkm-only mid barrier, deferred l-reduction. (R21-proven)
__global__ __launch_bounds__(256, 6) void attn_part(
    const unsigned short* __restrict__ Q,   // [BH, S, 64] bf16, pre-scaled
    const unsigned short* __restrict__ Kb,  // [BH, S, 64] bf16
    const unsigned short* __restrict__ Vt,  // [BH, 64, S] bf16, sigma-permuted
    unsigned short* __restrict__ pO,        // [1536][64][64] bf16
    float* __restrict__ pm,                 // [1536][64]
    float* __restrict__ pl,                 // [1536][64]
    unsigned short* __restrict__ Out)       // [B*S, 1024] bf16
{
  __shared__ __align__(16) char kbuf[64 * 128];
  __shared__ __align__(16) char vbuf[2][64 * 128];
  int t = threadIdx.x;
  int lane = t & 63, wid = t >> 6;
  int gi = lane >> 4, c0 = lane & 15;
  int bid = blockIdx.x + 48 * blockIdx.y;
  int xcd = bid & 7, local = bid >> 3;      // local in [0,192)
  int item = local >> 2;
  int bh = xcd * 4 + (local & 3);
  WorkItem wi = g_items[item];
  int qt = wi.qt, tile0 = wi.t0, nt = wi.nt;
  int pid = bh * 48 + (tile0 ? (32 + qt - 16) : qt);
  int q0 = qt << 6;
  const unsigned short* Qh = Q  + (size_t)bh * S_LEN * DKH;
  const unsigned short* Kh = Kb + (size_t)bh * S_LEN * DKH;
  const unsigned short* Vh = Vt + (size_t)bh * DKH * S_LEN;

  bf16x8 qf[2];
  {
    int qrow = q0 + wid * 16 + c0;
#pragma unroll
    for (int ks = 0; ks < 2; ++ks)
      qf[ks] = *(const bf16x8*)(Qh + (size_t)qrow * DKH + ks * 32 + gi * 8);
  }

  float mrow = -1e30f, lrow = 0.f;          // lrow: per-lane partial
  f32x4 o[4];
#pragma unroll
  for (int i = 0; i < 4; ++i) o[i] = (f32x4){0, 0, 0, 0};

  int rs = t >> 3, uP = t & 7;
  int q_abs = q0 + wid * 16 + c0;

  int c8 = uP ^ (rs & 7);
  const unsigned short* kp0 = Kh + ((size_t)(tile0 * 64 + rs) * DKH) + c8 * 8;
  const unsigned short* kp1 = kp0 + 32 * DKH;
  const unsigned short* vp0 = Vh + (size_t)rs * S_LEN + tile0 * 64 + c8 * 8;
  const unsigned short* vp1 = vp0 + (size_t)32 * S_LEN;
  char* klds0 = kbuf + rs * 128 + uP * 16;
  char* klds1 = klds0 + 32 * 128;
  int vlds_off0 = rs * 128 + uP * 16;

  gload_lds16(kp0, klds0);
  gload_lds16(kp1, klds1);
  gload_lds16(vp0, vbuf[0] + vlds_off0);
  gload_lds16(vp1, vbuf[0] + vlds_off0 + 32 * 128);
  kp0 += 64 * DKH; kp1 += 64 * DKH; vp0 += 64; vp1 += 64;

  for (int tt = 0; tt < nt; ++tt) {
    int tile = tile0 + tt;
    int kv0 = tile << 6;
    __syncthreads();   // vmcnt+lgkm drain: K(t), V(t) resident

    // EARLY V-stage for t+1 (V double-buffered; readers ordered by barrier)
    if (tt + 1 < nt) {
      char* vb = vbuf[(tt + 1) & 1];
      gload_lds16(vp0, vb + vlds_off0);
      gload_lds16(vp1, vb + vlds_off0 + 32 * 128);
      vp0 += 64; vp1 += 64;
    }

    f32x4 sc[4];
    __builtin_amdgcn_s_setprio(1);
#pragma unroll
    for (int f = 0; f < 4; ++f) {
      f32x4 s = (f32x4){0, 0, 0, 0};
#pragma unroll
      for (int ks = 0; ks < 2; ++ks) {
        int rb = f * 16 + c0;
        int uL = ks * 4 + gi;
        bf16x8 kf = *(const bf16x8*)(kbuf + rb * 128 + ((uL ^ (rb & 7)) * 16));
        s = __builtin_amdgcn_mfma_f32_16x16x32_bf16(kf, qf[ks], s, 0, 0, 0);
      }
      sc[f] = s;
    }
    __builtin_amdgcn_s_setprio(0);
    // mid barrier: lgkm-only; must NOT drain vmcnt (early V loads in flight)
    asm volatile("s_waitcnt lgkmcnt(0)" ::: "memory");
    __builtin_amdgcn_s_barrier();

    if (tt + 1 < nt) {                       // K stages after kbuf is free
      gload_lds16(kp0, klds0);
      gload_lds16(kp1, klds1);
      kp0 += 64 * DKH; kp1 += 64 * DKH;
    }

    if (tile == qt) {
      int kvb = kv0 + gi * 4;
#pragma unroll
      for (int f = 0; f < 4; ++f)
#pragma unroll
        for (int i = 0; i < 4; ++i)
          if (kvb + f * 16 + i > q_abs) sc[f][i] = -1e30f;
    }

    float m01 = fmaxf(fmaxf(sc[0][0], sc[0][1]), fmaxf(sc[0][2], sc[0][3]));
    float m23 = fmaxf(fmaxf(sc[1][0], sc[1][1]), fmaxf(sc[1][2], sc[1][3]));
    float m45 = fmaxf(fmaxf(sc[2][0], sc[2][1]), fmaxf(sc[2][2], sc[2][3]));
    float m67 = fmaxf(fmaxf(sc[3][0], sc[3][1]), fmaxf(sc[3][2], sc[3][3]));
    float tmax = fmaxf(fmaxf(m01, m23), fmaxf(m45, m67));
    tmax = fmaxf(tmax, __shfl_xor(tmax, 16));
    tmax = fmaxf(tmax, __shfl_xor(tmax, 32));

    float alpha = 1.f;
    if (__any(tmax > mrow + 8.f)) {   // T13 defer-max
      float mnew = fmaxf(mrow, tmax);
      alpha = exp2a(mrow - mnew);
      mrow = mnew;
      float af0 = __shfl(alpha, gi * 4 + 0);
      float af1 = __shfl(alpha, gi * 4 + 1);
      float af2 = __shfl(alpha, gi * 4 + 2);
      float af3 = __shfl(alpha, gi * 4 + 3);
#pragma unroll
      for (int df = 0; df < 4; ++df) {
        o[df][0] *= af0; o[df][1] *= af1; o[df][2] *= af2; o[df][3] *= af3;
      }
    }

    float ps0 = 0, ps1 = 0, ps2 = 0, ps3 = 0;
#pragma unroll
    for (int f = 0; f < 4; ++f) {
      float p0 = exp2a(sc[f][0] - mrow);
      float p1 = exp2a(sc[f][1] - mrow);
      float p2 = exp2a(sc[f][2] - mrow);
      float p3 = exp2a(sc[f][3] - mrow);
      sc[f][0] = p0; sc[f][1] = p1; sc[f][2] = p2; sc[f][3] = p3;
      ps0 += p0; ps1 += p1; ps2 += p2; ps3 += p3;
    }
    lrow = lrow * alpha + ((ps0 + ps1) + (ps2 + ps3));

    // P -> bf16: lane-local PV A-fragments (V rows sigma-permuted to match)
    {
      const char* vcur = vbuf[tt & 1];
#pragma unroll
      for (int ks = 0; ks < 2; ++ks) {
        union { unsigned int w[4]; bf16x8 v; } pa;
        pa.w[0] = cvtpk(sc[2 * ks][0],     sc[2 * ks][1]);
        pa.w[1] = cvtpk(sc[2 * ks][2],     sc[2 * ks][3]);
        pa.w[2] = cvtpk(sc[2 * ks + 1][0], sc[2 * ks + 1][1]);
        pa.w[3] = cvtpk(sc[2 * ks + 1][2], sc[2 * ks + 1][3]);
        __builtin_amdgcn_s_setprio(1);
#pragma unroll
        for (int df = 0; df < 4; ++df) {
          int rv = df * 16 + c0;
          int uL = ks * 4 + gi;
          bf16x8 vf = *(const bf16x8*)(vcur + rv * 128 + ((uL ^ (rv & 7)) * 16));
          o[df] = __builtin_amdgcn_mfma_f32_16x16x32_bf16(pa.v, vf, o[df], 0, 0, 0);
        }
        __builtin_amdgcn_s_setprio(0);
      }
    }
  }

  // epilogue: complete the deferred l-reduction (once per block)
  lrow += __shfl_xor(lrow, 16);
  lrow += __shfl_xor(lrow, 32);

  if (qt < 16) {
    // single-chunk row block: normalize here, write directly to Out
    int b = bh >> 4, h = bh & 15;
    float linv = 1.0f / lrow;                 // lane holds l for q-row c0
#pragma unroll
    for (int i = 0; i < 4; ++i) {
      float rli = __shfl(linv, gi * 4 + i);   // l for output row gi*4+i
      int r = wid * 16 + gi * 4 + i;
      size_t base = ((size_t)(b * S_LEN) + (q0 + r)) * DM + h * DKH;
#pragma unroll
      for (int df = 0; df < 4; ++df)
        Out[base + df * 16 + c0] = f2bf(o[df][i] * rli);
    }
  } else {
    unsigned short* po = pO + (size_t)pid * 4096;
#pragma unroll
    for (int i = 0; i < 4; ++i) {
      int r = wid * 16 + gi * 4 + i;
#pragma unroll
      for (int df = 0; df < 4; ++df)
        po[r * 64 + df * 16 + c0] = f2bf(o[df][i]);
    }
    if (lane < 16) {
      pm[pid * 64 + wid * 16 + c0] = mrow;
      pl[pid * 64 + wid * 16 + c0] = lrow;
    }
  }
}

// ---------------- combine partials (qt >= 16 only) -> Out ------------------
__global__ __launch_bounds__(256) void attn_combine(
    const unsigned short* __restrict__ pO,
    const float* __restrict__ pm,
    const float* __restrict__ pl,
    unsigned short* __restrict__ Out)
{
  int qt = blockIdx.x + 16, bh = blockIdx.y;
  int t = threadIdx.x;
  int r = t >> 2, cseg = (t & 3) * 16;
  int pid0 = bh * 48 + qt;
  int pid1 = bh * 48 + 32 + qt - 16;

  float m0 = pm[pid0 * 64 + r];
  float l0 = pl[pid0 * 64 + r];
  float m1 = pm[pid1 * 64 + r];
  float l1 = pl[pid1 * 64 + r];
  float M = fmaxf(m0, m1);
  float w0 = exp2a(m0 - M);
  float w1 = exp2a(m1 - M);
  float l = w0 * l0 + w1 * l1;
  float rl = 1.0f / l;

  const unsigned short* o0 = pO + (size_t)pid0 * 4096 + r * 64 + cseg;
  const unsigned short* o1 = pO + (size_t)pid1 * 4096 + r * 64 + cseg;
  int b = bh >> 4, h = bh & 15;
  size_t base = ((size_t)(b * S_LEN) + (qt * 64 + r)) * DM + h * DKH + cseg;

  bf16x8 a0 = *(const bf16x8*)o0;
  bf16x8 a1 = *(const bf16x8*)(o0 + 8);
  bf16x8 b0 = *(const bf16x8*)o1;
  bf16x8 b1 = *(const bf16x8*)(o1 + 8);
  unsigned short res[16];
#pragma unroll
  for (int j = 0; j < 8; ++j) {
    res[j]     = f2bf((w0 * bf2f((unsigned short)a0[j]) + w1 * bf2f((unsigned short)b0[j])) * rl);
    res[j + 8] = f2bf((w0 * bf2f((unsigned short)a1[j]) + w1 * bf2f((unsigned short)b1[j])) * rl);
  }
  *(u32x4*)(Out + base)     = *(u32x4*)res;
  *(u32x4*)(Out + base + 8) = *(u32x4*)(res + 8);
}

// ----------------------------------------------------------------------------
extern "C" void kernel_launch(void* const* d_in, const int* in_sizes, int n_in,
                              void* d_out, int out_size, void* d_ws, size_t ws_size,
                              hipStream_t stream) {
  const float* x       = (const float*)d_in[0];
  const float* w_atten = (const float*)d_in[1];
  const float* b_atten = (const float*)d_in[2];
  const float* w_proj  = (const float*)d_in[3];
  const float* b_proj  = (const float*)d_in[4];
  float* out = (float*)d_out;
  char* ws = (char*)d_ws;

  unsigned short* x_bf  = (unsigned short*)(ws);
  unsigned short* wa_bf = (unsigned short*)(ws + ((size_t)8  << 20));
  unsigned short* wp_bf = (unsigned short*)(ws + ((size_t)14 << 20));
  unsigned short* q_bf  = (unsigned short*)(ws + ((size_t)16 << 20));
  unsigned short* k_bf  = (unsigned short*)(ws + ((size_t)24 << 20));
  unsigned short* vt_bf = (unsigned short*)(ws + ((size_t)32 << 20));
  unsigned short* at_bf = (unsigned short*)(ws + ((size_t)40 << 20));
  // partial buffers overlay x_bf/wa_bf (dead after gemm0)
  unsigned short* pO = (unsigned short*)(ws);
  float* pm = (float*)(ws + 12582912);
  float* pl = (float*)(ws + 12976128);

  cvt_all<<<4096, 256, 0, stream>>>(x, w_atten, w_proj, x_bf, wa_bf, wp_bf);

  gemm_x<0><<<dim3(24, 32), 256, 0, stream>>>(x_bf, wa_bf, b_atten, nullptr,
                                              q_bf, k_bf, vt_bf, 4096, 3072, 1024);
  attn_part<<<dim3(48, 32), 256, 0, stream>>>(q_bf, k_bf, vt_bf, pO, pm, pl, at_bf);
  attn_combine<<<dim3(16, 32), 256, 0, stream>>>(pO, pm, pl, at_bf);
  gemm_h<<<dim3(16, 32), 256, 0, stream>>>(at_bf, wp_bf, b_proj, out,
                                           4096, 1024, 1024);
}